// Round 8
// baseline (26.234 us; speedup 1.0000x reference)
//
#include <hip/hip_runtime.h>

// Problem constants (fixed by the bench: B=8, L=512, T=4096, D=512).
constexpr int B = 8;
constexpr int L = 512;
constexpr int D = 512;
constexpr int T = 4096;

constexpr int OUT_REP = B * D * T;        // offset of repeats in d_out
constexpr int OUT_LAT = OUT_REP + B * L;  // offset of latent_lengths

// ---------------- kernel 1: per-batch scan + t->l LUT build (8 blocks) ----
__global__ __launch_bounds__(256) void scan_kernel(
    const float* __restrict__ dur,        // (B, L)
    float* __restrict__ out,              // for repeats / latent_lengths
    unsigned short* __restrict__ lut)     // ws: (B, T) u16, 0xFFFF = past end
{
    const int b    = blockIdx.x;
    const int tid  = threadIdx.x;
    const int lane = tid & 63;
    const int wave = tid >> 6;

    __shared__ unsigned short lsm[T];     // 8 KB LUT staging
    __shared__ int wave_tot[4];

    const float2 dur2 = *reinterpret_cast<const float2*>(dur + b * L + 2 * tid);

    // init LUT to 0xFFFF (2048 u32)
    #pragma unroll
    for (int i = 0; i < T / 2 / 256; ++i)
        reinterpret_cast<unsigned*>(lsm)[i * 256 + tid] = 0xFFFFFFFFu;

    const int r0 = (int)floorf(dur2.x + 0.5f);
    const int r1 = (int)floorf(dur2.y + 0.5f);
    const int pair = r0 + r1;

    int scan = pair;                      // wave-level inclusive scan
    #pragma unroll
    for (int off = 1; off < 64; off <<= 1) {
        int n = __shfl_up(scan, off, 64);
        if (lane >= off) scan += n;
    }
    if (lane == 63) wave_tot[wave] = scan;
    __syncthreads();                      // covers lut init + wave_tot

    int wpre = 0;
    #pragma unroll
    for (int w = 0; w < 4; ++w) wpre += (w < wave) ? wave_tot[w] : 0;
    int k = wpre + scan - pair;           // exclusive prefix = t-start of l0's span
    const int total = wave_tot[0] + wave_tot[1] + wave_tot[2] + wave_tot[3];

    // scatter: each l writes its own span
    const int l0 = 2 * tid;
    for (int q = 0; q < r0; ++q, ++k) if (k < T) lsm[k] = (unsigned short)l0;
    for (int q = 0; q < r1; ++q, ++k) if (k < T) lsm[k] = (unsigned short)(l0 + 1);

    // side outputs
    out[OUT_REP + b * L + l0]     = (float)r0;
    out[OUT_REP + b * L + l0 + 1] = (float)r1;
    if (tid == 0) out[OUT_LAT + b] = (float)total;
    __syncthreads();

    // coalesced dump LDS -> ws  (512 uint4)
    uint4*       dst = reinterpret_cast<uint4*>(lut + (size_t)b * T);
    const uint4* src = reinterpret_cast<const uint4*>(lsm);
    dst[tid]       = src[tid];
    dst[tid + 256] = src[tid + 256];
}

// ---------------- kernel 2: fill-shaped streaming expansion ---------------
// 16384 blocks; blockIdx.x == linear 4 KB chunk of `expanded`. In-order
// dispatch => the resident blocks cover a compact sliding address window,
// exactly like __amd_rocclr_fillBufferAligned (measured 6.4 TB/s).
__global__ __launch_bounds__(256) void expand_kernel(
    const float* __restrict__ enc,          // (B, D, L)
    const unsigned short* __restrict__ lut, // (B, T)
    float* __restrict__ out)                // (B, D, T)
{
    const int c   = blockIdx.x;             // 0..16383, linear memory order
    const int tid = threadIdx.x;

    const int b   = c >> 11;                // c / (D*4)
    const int rem = c & 2047;
    const int d   = rem >> 2;
    const int t   = ((rem & 3) << 10) + 4 * tid;   // t0 + 4*tid

    // 8 B coalesced LUT read (L2-hot)
    const uint2 lu = *reinterpret_cast<const uint2*>(lut + (size_t)b * T + t);
    const int la = lu.x & 0xffff, lb = lu.x >> 16;
    const int lc = lu.y & 0xffff, ld = lu.y >> 16;

    // gather from the single 2 KB enc row this block uses (L1-resident)
    const float* row = enc + ((size_t)b * D + d) * L;
    float4 v;
    v.x = row[la & 511];
    v.y = row[lb & 511];
    v.z = row[lc & 511];
    v.w = row[ld & 511];
    if (la == 0xffff) v.x = 0.0f;
    if (lb == 0xffff) v.y = 0.0f;
    if (lc == 0xffff) v.z = 0.0f;
    if (ld == 0xffff) v.w = 0.0f;

    // one float4 store per thread, globally linear: out4[c*256 + tid]
    reinterpret_cast<float4*>(out)[((size_t)c << 8) + tid] = v;
}

extern "C" void kernel_launch(void* const* d_in, const int* in_sizes, int n_in,
                              void* d_out, int out_size, void* d_ws, size_t ws_size,
                              hipStream_t stream) {
    const float* enc = (const float*)d_in[0];   // (B, D, L) fp32
    const float* dur = (const float*)d_in[1];   // (B, L)    fp32
    float* out = (float*)d_out;
    unsigned short* lut = (unsigned short*)d_ws;  // 64 KB

    scan_kernel<<<dim3(B), dim3(256), 0, stream>>>(dur, out, lut);
    expand_kernel<<<dim3(B * D * 4), dim3(256), 0, stream>>>(enc, lut, out);
}